// Round 8
// baseline (67.730 us; speedup 1.0000x reference)
//
#include <hip/hip_runtime.h>

// KalmanGain: B=262144, N=8, M=4, fp32.
// Round 8: intra-wave software pipeline across tiles (counted vmcnt, T3/T14).
//   Block = 64 threads (1 wave) processes TILES=8 tiles of NBB=16 batches,
//   double-buffered LDS (2 x 11 KB). Tile t+1's staging (F,H,Sp,R: 11
//   global_load_lds) is issued mid-tile-t and crosses the tile boundary in
//   flight; waits are counted (vmcnt 5/15/11), never a full drain except the
//   final tile. Single-wave block -> no s_barrier; sync = wave waitcnt only.
// Per-buffer granule map (float4): F/Q [0,256) | Sp [256,512) | H [512,640)
//   | R [640,704).  2 buffers = 22528 B -> 7 blocks/CU.
// vmcnt accounting (issue order F4,H2,Sp4,R1; stores are 2 newest at entry):
//   entry  vmcnt(5)  -> oldest 8 of 13 done => F,H(t) landed
//   after issuing Q(4)+FHSpR(t+1)(11): vmcnt(15) => Sp,R(t)+stores landed
//   before final phase: vmcnt(11) => Q(t) landed (FHSpR(t+1) still flying)
//   last tile: vmcnt(4) / vmcnt(0) variants (uniform branch).
// Any extra compiler vmem op only makes these waits MORE conservative (vmcnt
// completion is in-issue-order), never less - count-safe by construction.
// Math per tile = R6/R7 proven body (4 lanes/batch, 2 rows each, XOR swizzle).

#define NBB 16
#define THREADS 64
#define TILES 8
#define BUFG 704

#define WAITV(N) asm volatile("s_waitcnt vmcnt(" #N ")" ::: "memory")

__device__ __forceinline__ void gl_lds16(const float* src, float4* dst) {
    __builtin_amdgcn_global_load_lds(
        (const __attribute__((address_space(1))) unsigned int*)src,
        (__attribute__((address_space(3))) unsigned int*)dst,
        16, 0, 0);
}

// F (4 loads) then H (2 loads) -- the "oldest 6" the entry wait needs.
__device__ __forceinline__ void stage_FH(const float* Fg, const float* Hg,
                                         float4* buf, int gb0, int lane) {
    #pragma unroll
    for (int r = 0; r < 4; ++r) {
        int s = (r << 6) | lane;
        int b = s >> 4, j = s & 15, k = j ^ (b & 15);
        gl_lds16(Fg + (size_t)(gb0 + b) * 64 + k * 4, buf + (r << 6));
    }
    #pragma unroll
    for (int r = 0; r < 2; ++r) {
        int s = (r << 6) | lane;
        int b = s >> 3, j = s & 7, k = j ^ (b & 7);
        gl_lds16(Hg + (size_t)(gb0 + b) * 32 + k * 4, buf + 512 + (r << 6));
    }
}
// Sp (4 loads) then R (1 load) -- needed only by phase 2 / phase 3.
__device__ __forceinline__ void stage_SpR(const float* Spg, const float* Rg,
                                          float4* buf, int gb0, int lane) {
    #pragma unroll
    for (int r = 0; r < 4; ++r) {
        int s = (r << 6) | lane;
        int b = s >> 4, j = s & 15, k = j ^ (b & 15);
        gl_lds16(Spg + (size_t)(gb0 + b) * 64 + k * 4, buf + 256 + (r << 6));
    }
    {
        int s = lane;
        int b = s >> 2, j = s & 3, k = j ^ (b & 3);
        gl_lds16(Rg + (size_t)(gb0 + b) * 16 + k * 4, buf + 640);
    }
}

__global__ __launch_bounds__(THREADS) void kalman_gain_kernel(
    const float* __restrict__ Fg, const float* __restrict__ Hg,
    const float* __restrict__ Spg, const float* __restrict__ Qg,
    const float* __restrict__ Rg, float* __restrict__ out, int nb)
{
    __shared__ float4 smem4[2 * BUFG];   // 22528 B

    const int lane  = threadIdx.x;       // one wave
    const int b_loc = lane >> 2;         // 0..15
    const int p     = lane & 3;          // owns global rows 2p, 2p+1
    const int bm15  = b_loc & 15;
    const int bm7   = b_loc & 7;
    const int tile0 = blockIdx.x * TILES;

    // ---- prologue: stage tile 0 into buffer 0 ----
    stage_FH (Fg,  Hg, smem4, tile0 * NBB, lane);
    stage_SpR(Spg, Rg, smem4, tile0 * NBB, lane);

    #pragma unroll 2
    for (int t = 0; t < TILES; ++t) {
        float4* buf  = smem4 + (t & 1) * BUFG;
        float4* nbuf = smem4 + ((t + 1) & 1) * BUFG;
        const int gb0 = (tile0 + t) * NBB;
        const bool notlast = (t + 1 < TILES);

        WAITV(5);   // F,H of tile t landed (Sp tail/R/stores may fly)

        // ---- phase 1: hs, fr, u + butterflies ----
        float hs[8];
        #pragma unroll
        for (int j = 0; j < 4; ++j) {
            float4 v = buf[512 + b_loc * 8 + ((2 * j + (p >> 1)) ^ bm7)];
            hs[j*2+0] = (p & 1) ? v.z : v.x;
            hs[j*2+1] = (p & 1) ? v.w : v.y;
        }
        float fr[16];
        #pragma unroll
        for (int i = 0; i < 4; ++i) {
            float4 v = buf[b_loc * 16 + ((4 * p + i) ^ bm15)];
            fr[i*4+0] = v.x; fr[i*4+1] = v.y; fr[i*4+2] = v.z; fr[i*4+3] = v.w;
        }
        float u[32];
        #pragma unroll
        for (int x = 0; x < 32; ++x) u[x] = 0.f;
        #pragma unroll
        for (int rl = 0; rl < 2; ++rl)
            #pragma unroll
            for (int k = 0; k < 8; ++k)
                #pragma unroll
                for (int j = 0; j < 4; ++j)
                    u[k*4+j] += hs[j*2+rl] * fr[rl*8+k];
        #pragma unroll
        for (int x = 0; x < 32; ++x) u[x] += __shfl_xor(u[x], 1, 64);
        #pragma unroll
        for (int x = 0; x < 32; ++x) u[x] += __shfl_xor(u[x], 2, 64);

        // all F ds_reads complete before Q's LDS-write can land
        asm volatile("s_waitcnt lgkmcnt(0)" ::: "memory");

        // ---- issue Q(t) into buf's F-slot ----
        #pragma unroll
        for (int r = 0; r < 4; ++r) {
            int s2 = (r << 6) | lane;
            int b = s2 >> 4, j = s2 & 15, k = j ^ (b & 15);
            gl_lds16(Qg + (size_t)(gb0 + b) * 64 + k * 4, buf + (r << 6));
        }
        // ---- issue tile t+1 staging (crosses tile boundary in flight) ----
        if (notlast) {
            stage_FH (Fg,  Hg, nbuf, gb0 + NBB, lane);
            stage_SpR(Spg, Rg, nbuf, gb0 + NBB, lane);
            WAITV(15);   // Sp,R(t) + old stores landed; Q+next-stage fly
        } else {
            WAITV(4);    // Sp,R(t) + old stores landed; Q flies
        }

        // ---- phase 2: G = fr @ Sp, A = G @ u ----
        float G[16];
        #pragma unroll
        for (int x = 0; x < 16; ++x) G[x] = 0.f;
        #pragma unroll
        for (int k = 0; k < 8; ++k) {
            float4 s0 = buf[256 + b_loc * 16 + ((2*k    ) ^ bm15)];
            float4 s1 = buf[256 + b_loc * 16 + ((2*k + 1) ^ bm15)];
            float sp[8] = {s0.x,s0.y,s0.z,s0.w, s1.x,s1.y,s1.z,s1.w};
            #pragma unroll
            for (int il = 0; il < 2; ++il)
                #pragma unroll
                for (int c = 0; c < 8; ++c)
                    G[il*8+c] += fr[il*8+k] * sp[c];
        }
        float A[8];
        #pragma unroll
        for (int il = 0; il < 2; ++il)
            #pragma unroll
            for (int j = 0; j < 4; ++j) {
                float acc = 0.f;
                #pragma unroll
                for (int k = 0; k < 8; ++k)
                    acc += G[il*8+k] * u[k*4+j];
                A[il*4+j] = acc;
            }

        if (notlast) { WAITV(11); } else { WAITV(0); }   // Q(t) landed

        // ---- phase 3: A += Qown @ H^T ; S = H A + R ; inv ; KG ; store ----
        float qo[16];
        #pragma unroll
        for (int i = 0; i < 4; ++i) {
            float4 v = buf[b_loc * 16 + ((4 * p + i) ^ bm15)];
            qo[i*4+0] = v.x; qo[i*4+1] = v.y; qo[i*4+2] = v.z; qo[i*4+3] = v.w;
        }
        #pragma unroll
        for (int j = 0; j < 4; ++j) {
            float4 h0 = buf[512 + b_loc * 8 + ((2*j    ) ^ bm7)];
            float4 h1 = buf[512 + b_loc * 8 + ((2*j + 1) ^ bm7)];
            float hrow[8] = {h0.x,h0.y,h0.z,h0.w, h1.x,h1.y,h1.z,h1.w};
            #pragma unroll
            for (int il = 0; il < 2; ++il) {
                float acc = 0.f;
                #pragma unroll
                for (int k = 0; k < 8; ++k)
                    acc += qo[il*8+k] * hrow[k];
                A[il*4+j] += acc;
            }
        }
        float4 Rr = buf[640 + b_loc * 4 + (p ^ (b_loc & 3))];
        float s[16];
        #pragma unroll
        for (int pi = 0; pi < 4; ++pi) {
            float rrow[4] = {Rr.x, Rr.y, Rr.z, Rr.w};
            #pragma unroll
            for (int q = 0; q < 4; ++q) {
                float acc = (pi == p) ? rrow[q] : 0.f;
                #pragma unroll
                for (int il = 0; il < 2; ++il)
                    acc += hs[pi*2+il] * A[il*4+q];
                s[pi*4+q] = acc;
            }
        }
        #pragma unroll
        for (int x = 0; x < 16; ++x) s[x] += __shfl_xor(s[x], 1, 64);
        #pragma unroll
        for (int x = 0; x < 16; ++x) s[x] += __shfl_xor(s[x], 2, 64);

        float is[16] = {1.f,0.f,0.f,0.f, 0.f,1.f,0.f,0.f,
                        0.f,0.f,1.f,0.f, 0.f,0.f,0.f,1.f};
        #pragma unroll
        for (int c = 0; c < 4; ++c) {
            float pinv = 1.0f / s[c*4+c];
            #pragma unroll
            for (int k = 0; k < 4; ++k) { s[c*4+k] *= pinv; is[c*4+k] *= pinv; }
            #pragma unroll
            for (int r = 0; r < 4; ++r) {
                if (r != c) {
                    float fac = s[r*4+c];
                    #pragma unroll
                    for (int k = 0; k < 4; ++k) {
                        s[r*4+k]  -= fac * s[c*4+k];
                        is[r*4+k] -= fac * is[c*4+k];
                    }
                }
            }
        }

        float4* outg = reinterpret_cast<float4*>(out)
                     + (size_t)(gb0 + b_loc) * 8 + 2 * p;
        #pragma unroll
        for (int il = 0; il < 2; ++il) {
            float4 o;
            o.x = A[il*4+0]*is[0] + A[il*4+1]*is[4] + A[il*4+2]*is[8]  + A[il*4+3]*is[12];
            o.y = A[il*4+0]*is[1] + A[il*4+1]*is[5] + A[il*4+2]*is[9]  + A[il*4+3]*is[13];
            o.z = A[il*4+0]*is[2] + A[il*4+1]*is[6] + A[il*4+2]*is[10] + A[il*4+3]*is[14];
            o.w = A[il*4+0]*is[3] + A[il*4+1]*is[7] + A[il*4+2]*is[11] + A[il*4+3]*is[15];
            outg[il] = o;   // 2 stores: the "2 newest" at next entry wait
        }
    }
}

extern "C" void kernel_launch(void* const* d_in, const int* in_sizes, int n_in,
                              void* d_out, int out_size, void* d_ws, size_t ws_size,
                              hipStream_t stream) {
    const float* F  = (const float*)d_in[0];
    const float* H  = (const float*)d_in[1];
    const float* Sp = (const float*)d_in[2];
    const float* Q  = (const float*)d_in[3];
    const float* R  = (const float*)d_in[4];
    float* out = (float*)d_out;

    int nb = in_sizes[0] / 64;              // B = 262144
    int blocks = nb / (NBB * TILES);        // 2048
    kalman_gain_kernel<<<blocks, THREADS, 0, stream>>>(F, H, Sp, Q, R, out, nb);
}

// Round 9
// 51.312 us; speedup vs baseline: 1.3200x; 1.3200x over previous
//
#include <hip/hip_runtime.h>

// KalmanGain: B=262144, N=8, M=4, fp32.
// Round 9: R6 structure/math, but LINEAR global staging + pitch-65 LDS pad.
//   Theory: R4-R7's XOR-swizzled gl_lds *global* addresses (lane-permuted,
//   line-crossing) throttle the per-CU TA request path. Fix: stage each 1KB
//   wave-row with LDS pitch 65 granules (16B pad/row). Global source is then
//   perfectly linear (lane L -> base + 16L). Pitch 65 (65%8==1) makes the hot
//   LDS reads conflict-free by construction:
//     fr/qo: slot%8 = (rF+4p+i)%8  -> uniform over 8 clusters (free)
//     Sp   : 4 clusters = 2-way (free, m136)
//     H    : ~3 clusters = mild 4-way on 12 reads/tile (negligible)
// Block = 256 threads (4 waves), 64 batches, 4 lanes/batch (2 rows each).
// LDS granule map (float4, pitch-65 rows):
//   F/Q [0,1040) | Sp [1040,2080) | H [2080,2600)  = 41600 B -> 3 blocks/CU.
// R: lane p loads granule 4b+p directly (coalesced, no LDS).
// Schedule (R4/R6-proven): stage F,H,Sp ; sync ; fr,hs,u+butterflies ; sync ;
//   issue Q into F slots ; G=fr@Sp ; A=G@u ; sync ; A+=Q@H^T ; S=HA+R ;
//   butterflies ; inv(S) ; KG ; store.

#define NBB 64
#define THREADS 256

__device__ __forceinline__ void gl_lds16(const float* src, float4* dst) {
    __builtin_amdgcn_global_load_lds(
        (const __attribute__((address_space(1))) unsigned int*)src,
        (__attribute__((address_space(3))) unsigned int*)dst,
        16, 0, 0);
}

__global__ __launch_bounds__(THREADS) void kalman_gain_kernel(
    const float* __restrict__ Fg, const float* __restrict__ Hg,
    const float* __restrict__ Spg, const float* __restrict__ Qg,
    const float* __restrict__ Rg, float* __restrict__ out, int nb)
{
    __shared__ float4 smem4[2600];   // 41600 B

    const int tid  = threadIdx.x;
    const int wid  = tid >> 6;       // wave 0..3
    const int lane = tid & 63;
    const int b0   = blockIdx.x * NBB;

    // ---- stage F (rows wid,wid+4,wid+8,wid+12), linear src, pitch-65 dest ----
    #pragma unroll
    for (int r4 = 0; r4 < 4; ++r4) {             // F: 16 wave-rows
        int r = r4 * 4 + wid;                    // row r = batches 4r..4r+3
        gl_lds16(Fg + (size_t)(b0 + 4 * r) * 64 + lane * 4, smem4 + r * 65);
    }
    #pragma unroll
    for (int r2 = 0; r2 < 2; ++r2) {             // H: 8 wave-rows
        int r = r2 * 4 + wid;                    // row r = batches 8r..8r+7
        gl_lds16(Hg + (size_t)(b0 + 8 * r) * 32 + lane * 4, smem4 + 2080 + r * 65);
    }
    #pragma unroll
    for (int r4 = 0; r4 < 4; ++r4) {             // Sp: 16 wave-rows
        int r = r4 * 4 + wid;
        gl_lds16(Spg + (size_t)(b0 + 4 * r) * 64 + lane * 4, smem4 + 1040 + r * 65);
    }

    const int b_loc = tid >> 2;      // 0..63
    const int p     = tid & 3;       // owns global rows 2p, 2p+1
    const int baseF  = (b_loc >> 2) * 65 + (b_loc & 3) * 16;
    const int baseSp = 1040 + baseF;
    const int baseH  = 2080 + (b_loc >> 3) * 65 + (b_loc & 7) * 8;

    // ---- R own row: lane p loads granule 4*b + p (fully coalesced) ----
    const float4 Rr = *(reinterpret_cast<const float4*>(Rg)
                        + (size_t)(b0 + b_loc) * 4 + p);

    __syncthreads();   // drains staging

    // ---- hs[j][rl] = H[j][2p+rl], rl=0..1 (value select on p&1) ----
    float hs[8];
    #pragma unroll
    for (int j = 0; j < 4; ++j) {
        float4 v = smem4[baseH + 2 * j + (p >> 1)];
        hs[j*2+0] = (p & 1) ? v.z : v.x;
        hs[j*2+1] = (p & 1) ? v.w : v.y;
    }

    // ---- fr = own 2 F rows [2][8] (granules 4p..4p+3) ----
    float fr[16];
    #pragma unroll
    for (int i = 0; i < 4; ++i) {
        float4 v = smem4[baseF + 4 * p + i];
        fr[i*4+0] = v.x; fr[i*4+1] = v.y; fr[i*4+2] = v.z; fr[i*4+3] = v.w;
    }

    // ---- u = (H F)^T [8][4]: own-row partial, 2-stage butterfly ----
    float u[32];
    #pragma unroll
    for (int x = 0; x < 32; ++x) u[x] = 0.f;
    #pragma unroll
    for (int rl = 0; rl < 2; ++rl)
        #pragma unroll
        for (int k = 0; k < 8; ++k)
            #pragma unroll
            for (int j = 0; j < 4; ++j)
                u[k*4+j] += hs[j*2+rl] * fr[rl*8+k];
    #pragma unroll
    for (int x = 0; x < 32; ++x) u[x] += __shfl_xor(u[x], 1, 64);
    #pragma unroll
    for (int x = 0; x < 32; ++x) u[x] += __shfl_xor(u[x], 2, 64);

    __syncthreads();   // all lanes done reading F LDS -> F buffer reusable

    // ---- issue Q into F's LDS rows (hidden under G/A compute) ----
    #pragma unroll
    for (int r4 = 0; r4 < 4; ++r4) {
        int r = r4 * 4 + wid;
        gl_lds16(Qg + (size_t)(b0 + 4 * r) * 64 + lane * 4, smem4 + r * 65);
    }

    // ---- G = own F rows @ Sp  [2][8] (stream Sp rows from LDS) ----
    float G[16];
    #pragma unroll
    for (int x = 0; x < 16; ++x) G[x] = 0.f;
    #pragma unroll
    for (int k = 0; k < 8; ++k) {
        float4 s0 = smem4[baseSp + 2*k    ];
        float4 s1 = smem4[baseSp + 2*k + 1];
        float sp[8] = {s0.x,s0.y,s0.z,s0.w, s1.x,s1.y,s1.z,s1.w};
        #pragma unroll
        for (int il = 0; il < 2; ++il)
            #pragma unroll
            for (int c = 0; c < 8; ++c)
                G[il*8+c] += fr[il*8+k] * sp[c];
    }

    // ---- A = G @ u  [2][4] ----
    float A[8];
    #pragma unroll
    for (int il = 0; il < 2; ++il)
        #pragma unroll
        for (int j = 0; j < 4; ++j) {
            float acc = 0.f;
            #pragma unroll
            for (int k = 0; k < 8; ++k)
                acc += G[il*8+k] * u[k*4+j];
            A[il*4+j] = acc;
        }

    __syncthreads();   // drains Q staging

    // ---- A += Qown @ H^T ----
    float qo[16];
    #pragma unroll
    for (int i = 0; i < 4; ++i) {
        float4 v = smem4[baseF + 4 * p + i];
        qo[i*4+0] = v.x; qo[i*4+1] = v.y; qo[i*4+2] = v.z; qo[i*4+3] = v.w;
    }
    #pragma unroll
    for (int j = 0; j < 4; ++j) {
        float4 h0 = smem4[baseH + 2*j    ];
        float4 h1 = smem4[baseH + 2*j + 1];
        float hrow[8] = {h0.x,h0.y,h0.z,h0.w, h1.x,h1.y,h1.z,h1.w};
        #pragma unroll
        for (int il = 0; il < 2; ++il) {
            float acc = 0.f;
            #pragma unroll
            for (int k = 0; k < 8; ++k)
                acc += qo[il*8+k] * hrow[k];
            A[il*4+j] += acc;
        }
    }

    // ---- S = H A + R: own partial (+own R row), 2-stage butterfly ----
    float s[16];
    #pragma unroll
    for (int pi = 0; pi < 4; ++pi) {
        float rrow[4] = {Rr.x, Rr.y, Rr.z, Rr.w};
        #pragma unroll
        for (int q = 0; q < 4; ++q) {
            float acc = (pi == p) ? rrow[q] : 0.f;   // own R row, added once
            #pragma unroll
            for (int il = 0; il < 2; ++il)
                acc += hs[pi*2+il] * A[il*4+q];
            s[pi*4+q] = acc;
        }
    }
    #pragma unroll
    for (int x = 0; x < 16; ++x) s[x] += __shfl_xor(s[x], 1, 64);
    #pragma unroll
    for (int x = 0; x < 16; ++x) s[x] += __shfl_xor(s[x], 2, 64);

    // ---- invert S (4x4 SPD), unrolled Gauss-Jordan ----
    float is[16] = {1.f,0.f,0.f,0.f, 0.f,1.f,0.f,0.f, 0.f,0.f,1.f,0.f, 0.f,0.f,0.f,1.f};
    #pragma unroll
    for (int c = 0; c < 4; ++c) {
        float pinv = 1.0f / s[c*4+c];
        #pragma unroll
        for (int k = 0; k < 4; ++k) { s[c*4+k] *= pinv; is[c*4+k] *= pinv; }
        #pragma unroll
        for (int r = 0; r < 4; ++r) {
            if (r != c) {
                float fac = s[r*4+c];
                #pragma unroll
                for (int k = 0; k < 4; ++k) {
                    s[r*4+k]  -= fac * s[c*4+k];
                    is[r*4+k] -= fac * is[c*4+k];
                }
            }
        }
    }

    // ---- KG own 2 rows = A @ inv(S); store (wave-contiguous) ----
    float4* outg = reinterpret_cast<float4*>(out)
                 + (size_t)(b0 + b_loc) * 8 + 2 * p;
    #pragma unroll
    for (int il = 0; il < 2; ++il) {
        float4 o;
        o.x = A[il*4+0]*is[0] + A[il*4+1]*is[4] + A[il*4+2]*is[8]  + A[il*4+3]*is[12];
        o.y = A[il*4+0]*is[1] + A[il*4+1]*is[5] + A[il*4+2]*is[9]  + A[il*4+3]*is[13];
        o.z = A[il*4+0]*is[2] + A[il*4+1]*is[6] + A[il*4+2]*is[10] + A[il*4+3]*is[14];
        o.w = A[il*4+0]*is[3] + A[il*4+1]*is[7] + A[il*4+2]*is[11] + A[il*4+3]*is[15];
        outg[il] = o;
    }
}

extern "C" void kernel_launch(void* const* d_in, const int* in_sizes, int n_in,
                              void* d_out, int out_size, void* d_ws, size_t ws_size,
                              hipStream_t stream) {
    const float* F  = (const float*)d_in[0];
    const float* H  = (const float*)d_in[1];
    const float* Sp = (const float*)d_in[2];
    const float* Q  = (const float*)d_in[3];
    const float* R  = (const float*)d_in[4];
    float* out = (float*)d_out;

    int nb = in_sizes[0] / 64;          // B = 262144 (divisible by 64)
    int blocks = nb / NBB;              // 4096
    kalman_gain_kernel<<<blocks, THREADS, 0, stream>>>(F, H, Sp, Q, R, out, nb);
}

// Round 11
// 49.294 us; speedup vs baseline: 1.3740x; 1.0410x over previous
//
#include <hip/hip_runtime.h>

// KalmanGain: B=262144, N=8, M=4, fp32.
// Round 11: R10 (minimal-stall + nontemporal stores), compile fix only:
//   __builtin_nontemporal_store needs a clang ext_vector_type pointer, not
//   HIP_vector_type float4. Store via float ext_vector_type(4) alias.
//   Block = 64 threads (1 wave), 16 batches, 4 lanes/batch (2 rows each).
//   ALL five inputs staged upfront (Q own buffer, R in LDS); exactly ONE
//   sync; straight-line compute to stores. 15.6 KB LDS -> 10 blocks/CU.
// LDS (float4 granules, pitch-65 per 64-granule wave-row, linear global src):
//   F [0,260) | Sp [260,520) | H [520,650) | Q [650,910) | R [910,974).
// Math (R6-proven): u=(HF)^T partial + butterflies; G=Fown@Sp; A=G@u;
//   A+=Qown@H^T; S=HA+R (butterflies); inv(S) Gauss-Jordan; KG=A inv(S).

#define NBB 16
#define THREADS 64

typedef float floatx4 __attribute__((ext_vector_type(4)));

__device__ __forceinline__ void gl_lds16(const float* src, float4* dst) {
    __builtin_amdgcn_global_load_lds(
        (const __attribute__((address_space(1))) unsigned int*)src,
        (__attribute__((address_space(3))) unsigned int*)dst,
        16, 0, 0);
}

__global__ __launch_bounds__(THREADS) void kalman_gain_kernel(
    const float* __restrict__ Fg, const float* __restrict__ Hg,
    const float* __restrict__ Spg, const float* __restrict__ Qg,
    const float* __restrict__ Rg, float* __restrict__ out, int nb)
{
    __shared__ float4 smem4[974];    // 15584 B -> 10 blocks/CU

    const int lane = threadIdx.x;    // one wave
    const int b0   = blockIdx.x * NBB;

    // ---- stage everything upfront: F(4), Sp(4), H(2), Q(4), R(1) ----
    #pragma unroll
    for (int r = 0; r < 4; ++r)      // F rows: batches 4r..4r+3
        gl_lds16(Fg + (size_t)(b0 + 4 * r) * 64 + lane * 4, smem4 + r * 65);
    #pragma unroll
    for (int r = 0; r < 4; ++r)      // Sp
        gl_lds16(Spg + (size_t)(b0 + 4 * r) * 64 + lane * 4, smem4 + 260 + r * 65);
    #pragma unroll
    for (int r = 0; r < 2; ++r)      // H rows: batches 8r..8r+7
        gl_lds16(Hg + (size_t)(b0 + 8 * r) * 32 + lane * 4, smem4 + 520 + r * 65);
    #pragma unroll
    for (int r = 0; r < 4; ++r)      // Q
        gl_lds16(Qg + (size_t)(b0 + 4 * r) * 64 + lane * 4, smem4 + 650 + r * 65);
    gl_lds16(Rg + (size_t)b0 * 16 + lane * 4, smem4 + 910);   // R (64 granules)

    const int b_loc = lane >> 2;     // 0..15
    const int p     = lane & 3;      // owns global rows 2p, 2p+1
    const int baseF  = (b_loc >> 2) * 65 + (b_loc & 3) * 16;
    const int baseSp = 260 + baseF;
    const int baseH  = 520 + (b_loc >> 3) * 65 + (b_loc & 7) * 8;
    const int baseQ  = 650 + baseF;

    __syncthreads();   // the ONLY sync: staging drain (1-wave block)

    // ---- R own row: granule 910 + lane (conflict-free) ----
    const float4 Rr = smem4[910 + lane];

    // ---- hs[j][rl] = H[j][2p+rl] (value select on p&1) ----
    float hs[8];
    #pragma unroll
    for (int j = 0; j < 4; ++j) {
        float4 v = smem4[baseH + 2 * j + (p >> 1)];
        hs[j*2+0] = (p & 1) ? v.z : v.x;
        hs[j*2+1] = (p & 1) ? v.w : v.y;
    }

    // ---- fr = own 2 F rows [2][8] ----
    float fr[16];
    #pragma unroll
    for (int i = 0; i < 4; ++i) {
        float4 v = smem4[baseF + 4 * p + i];
        fr[i*4+0] = v.x; fr[i*4+1] = v.y; fr[i*4+2] = v.z; fr[i*4+3] = v.w;
    }

    // ---- u = (H F)^T [8][4]: own-row partial, 2-stage butterfly ----
    float u[32];
    #pragma unroll
    for (int x = 0; x < 32; ++x) u[x] = 0.f;
    #pragma unroll
    for (int rl = 0; rl < 2; ++rl)
        #pragma unroll
        for (int k = 0; k < 8; ++k)
            #pragma unroll
            for (int j = 0; j < 4; ++j)
                u[k*4+j] += hs[j*2+rl] * fr[rl*8+k];
    #pragma unroll
    for (int x = 0; x < 32; ++x) u[x] += __shfl_xor(u[x], 1, 64);
    #pragma unroll
    for (int x = 0; x < 32; ++x) u[x] += __shfl_xor(u[x], 2, 64);

    // ---- G = own F rows @ Sp  [2][8] ----
    float G[16];
    #pragma unroll
    for (int x = 0; x < 16; ++x) G[x] = 0.f;
    #pragma unroll
    for (int k = 0; k < 8; ++k) {
        float4 s0 = smem4[baseSp + 2*k    ];
        float4 s1 = smem4[baseSp + 2*k + 1];
        float sp[8] = {s0.x,s0.y,s0.z,s0.w, s1.x,s1.y,s1.z,s1.w};
        #pragma unroll
        for (int il = 0; il < 2; ++il)
            #pragma unroll
            for (int c = 0; c < 8; ++c)
                G[il*8+c] += fr[il*8+k] * sp[c];
    }

    // ---- A = G @ u  [2][4] ----
    float A[8];
    #pragma unroll
    for (int il = 0; il < 2; ++il)
        #pragma unroll
        for (int j = 0; j < 4; ++j) {
            float acc = 0.f;
            #pragma unroll
            for (int k = 0; k < 8; ++k)
                acc += G[il*8+k] * u[k*4+j];
            A[il*4+j] = acc;
        }

    // ---- A += Qown @ H^T ----
    float qo[16];
    #pragma unroll
    for (int i = 0; i < 4; ++i) {
        float4 v = smem4[baseQ + 4 * p + i];
        qo[i*4+0] = v.x; qo[i*4+1] = v.y; qo[i*4+2] = v.z; qo[i*4+3] = v.w;
    }
    #pragma unroll
    for (int j = 0; j < 4; ++j) {
        float4 h0 = smem4[baseH + 2*j    ];
        float4 h1 = smem4[baseH + 2*j + 1];
        float hrow[8] = {h0.x,h0.y,h0.z,h0.w, h1.x,h1.y,h1.z,h1.w};
        #pragma unroll
        for (int il = 0; il < 2; ++il) {
            float acc = 0.f;
            #pragma unroll
            for (int k = 0; k < 8; ++k)
                acc += qo[il*8+k] * hrow[k];
            A[il*4+j] += acc;
        }
    }

    // ---- S = H A + R: own partial (+own R row), 2-stage butterfly ----
    float s[16];
    #pragma unroll
    for (int pi = 0; pi < 4; ++pi) {
        float rrow[4] = {Rr.x, Rr.y, Rr.z, Rr.w};
        #pragma unroll
        for (int q = 0; q < 4; ++q) {
            float acc = (pi == p) ? rrow[q] : 0.f;   // own R row, added once
            #pragma unroll
            for (int il = 0; il < 2; ++il)
                acc += hs[pi*2+il] * A[il*4+q];
            s[pi*4+q] = acc;
        }
    }
    #pragma unroll
    for (int x = 0; x < 16; ++x) s[x] += __shfl_xor(s[x], 1, 64);
    #pragma unroll
    for (int x = 0; x < 16; ++x) s[x] += __shfl_xor(s[x], 2, 64);

    // ---- invert S (4x4 SPD), unrolled Gauss-Jordan ----
    float is[16] = {1.f,0.f,0.f,0.f, 0.f,1.f,0.f,0.f, 0.f,0.f,1.f,0.f, 0.f,0.f,0.f,1.f};
    #pragma unroll
    for (int c = 0; c < 4; ++c) {
        float pinv = 1.0f / s[c*4+c];
        #pragma unroll
        for (int k = 0; k < 4; ++k) { s[c*4+k] *= pinv; is[c*4+k] *= pinv; }
        #pragma unroll
        for (int r = 0; r < 4; ++r) {
            if (r != c) {
                float fac = s[r*4+c];
                #pragma unroll
                for (int k = 0; k < 4; ++k) {
                    s[r*4+k]  -= fac * s[c*4+k];
                    is[r*4+k] -= fac * is[c*4+k];
                }
            }
        }
    }

    // ---- KG own 2 rows = A @ inv(S); NONTEMPORAL store via clang vec type ----
    floatx4* outg = reinterpret_cast<floatx4*>(out)
                  + (size_t)(b0 + b_loc) * 8 + 2 * p;
    #pragma unroll
    for (int il = 0; il < 2; ++il) {
        floatx4 o;
        o.x = A[il*4+0]*is[0] + A[il*4+1]*is[4] + A[il*4+2]*is[8]  + A[il*4+3]*is[12];
        o.y = A[il*4+0]*is[1] + A[il*4+1]*is[5] + A[il*4+2]*is[9]  + A[il*4+3]*is[13];
        o.z = A[il*4+0]*is[2] + A[il*4+1]*is[6] + A[il*4+2]*is[10] + A[il*4+3]*is[14];
        o.w = A[il*4+0]*is[3] + A[il*4+1]*is[7] + A[il*4+2]*is[11] + A[il*4+3]*is[15];
        __builtin_nontemporal_store(o, outg + il);
    }
}

extern "C" void kernel_launch(void* const* d_in, const int* in_sizes, int n_in,
                              void* d_out, int out_size, void* d_ws, size_t ws_size,
                              hipStream_t stream) {
    const float* F  = (const float*)d_in[0];
    const float* H  = (const float*)d_in[1];
    const float* Sp = (const float*)d_in[2];
    const float* Q  = (const float*)d_in[3];
    const float* R  = (const float*)d_in[4];
    float* out = (float*)d_out;

    int nb = in_sizes[0] / 64;          // B = 262144 (divisible by 16)
    int blocks = nb / NBB;              // 16384
    kalman_gain_kernel<<<blocks, THREADS, 0, stream>>>(F, H, Sp, Q, R, out, nb);
}